// Round 2
// baseline (460.120 us; speedup 1.0000x reference)
//
#include <hip/hip_runtime.h>
#include <hip/hip_bf16.h>
#include <math.h>

#define N_NODES 100000
#define N_EDGES 1600000
#define IN_CH 128
#define OUT_CH 128
#define EDGE_DIM 6
#define STATE_DIM 5
#define XS_DIM 133          // IN_CH + STATE_DIM
#define KPAD 160            // 5 k-steps of 32
#define NKSTEP 5
#define ASTRIDE 168         // LDS row stride (bf16 elems)
#define NBLK 391            // ceil(N_NODES/256)
#define N_CHUNKS 25000      // N_EDGES / 64  (exact)

typedef short s16x8 __attribute__((ext_vector_type(8)));
typedef float f32x4 __attribute__((ext_vector_type(4)));
typedef _Float16 h16x2 __attribute__((ext_vector_type(2)));

static __device__ __forceinline__ unsigned short f2bf(float f) {
    __hip_bfloat16 h = __float2bfloat16(f);   // RNE
    return *reinterpret_cast<unsigned short*>(&h);
}
static __device__ __forceinline__ unsigned f2h(float f) {   // f32 -> f16 bits
    _Float16 h = (_Float16)f;                 // RNE hardware convert
    return (unsigned)__builtin_bit_cast(unsigned short, h);
}
static __device__ __forceinline__ float bflo(unsigned u) {   // low bf16 -> f32
    return __uint_as_float(u << 16);
}
static __device__ __forceinline__ float bfhi(unsigned u) {   // high bf16 -> f32
    return __uint_as_float(u & 0xffff0000u);
}

// 2-term f16 dot with f32 accumulate: one v_dot2_f32_f16
static __device__ __forceinline__ float dot2f(unsigned a, h16x2 b, float c) {
#if __has_builtin(__builtin_amdgcn_fdot2)
    return __builtin_amdgcn_fdot2(__builtin_bit_cast(h16x2, a), b, c, false);
#else
    h16x2 av = __builtin_bit_cast(h16x2, a);
    return fmaf((float)av[0], (float)b[0], fmaf((float)av[1], (float)b[1], c));
#endif
}

// ---------------------------------------------------------------------------
// Repack W_neg[0:133], W_root into MFMA B-fragment order, bf16, K padded 160.
// ---------------------------------------------------------------------------
__global__ __launch_bounds__(64) void repack_w(
    const float* __restrict__ Wneg, const float* __restrict__ Wroot,
    unsigned short* __restrict__ Pneg, unsigned short* __restrict__ Proot)
{
    int b = blockIdx.x;
    int mat = b / 40, r = b % 40;
    int kk = r / 8, nt = r % 8;
    int lane = threadIdx.x;
    const float* W = mat ? Wroot : Wneg;
    unsigned short* P = mat ? Proot : Pneg;
    int n = nt * 16 + (lane & 15);
    int kb = kk * 32 + (lane >> 4) * 8;
    unsigned short v[8];
#pragma unroll
    for (int j = 0; j < 8; ++j) {
        int k = kb + j;
        v[j] = (k < XS_DIM) ? f2bf(W[k * 128 + n]) : (unsigned short)0;
    }
    *(s16x8*)(P + ((size_t)(kk * 8 + nt) * 64 + lane) * 8) = *(s16x8*)v;
}

// ---------------------------------------------------------------------------
// MFMA node GEMM: 64 nodes/block, 4 waves.
// ---------------------------------------------------------------------------
__global__ __launch_bounds__(256) void node_gemm_mfma(
    const float* __restrict__ x, const float* __restrict__ gs,
    const unsigned short* __restrict__ Pneg, const unsigned short* __restrict__ Proot,
    const float* __restrict__ bneg, const float* __restrict__ broot,
    __hip_bfloat16* __restrict__ Yb, float* __restrict__ out)
{
    __shared__ unsigned short Alds[64 * ASTRIDE];
    const int tid  = threadIdx.x;
    const int lane = tid & 63;
    const int wv   = tid >> 6;
    const int n0   = blockIdx.x * 64;

#pragma unroll
    for (int i = 0; i < 16; ++i) {
        int row = i * 4 + wv;
        int nn  = min(n0 + row, N_NODES - 1);
        const float2 v = *(const float2*)(x + (size_t)nn * IN_CH + lane * 2);
        Alds[row * ASTRIDE + lane * 2]     = f2bf(v.x);
        Alds[row * ASTRIDE + lane * 2 + 1] = f2bf(v.y);
    }
    if (tid < 64) {
        int nn = min(n0 + tid, N_NODES - 1);
#pragma unroll
        for (int j = 0; j < STATE_DIM; ++j)
            Alds[tid * ASTRIDE + IN_CH + j] = f2bf(gs[(size_t)nn * STATE_DIM + j]);
#pragma unroll
        for (int k = XS_DIM; k < KPAD; ++k)
            Alds[tid * ASTRIDE + k] = 0;
    }
    __syncthreads();

    f32x4 accN[8], accR[8];
    const f32x4 zero = {0.f, 0.f, 0.f, 0.f};
#pragma unroll
    for (int nt = 0; nt < 8; ++nt) { accN[nt] = zero; accR[nt] = zero; }

    const int m = lane & 15, quad = lane >> 4;
    const unsigned short* arow = Alds + (wv * 16 + m) * ASTRIDE + quad * 8;

    for (int kk = 0; kk < NKSTEP; ++kk) {
        s16x8 a = *(const s16x8*)(arow + kk * 32);
        const unsigned short* bp = Pneg  + ((size_t)kk * 8 * 64 + lane) * 8;
        const unsigned short* rp = Proot + ((size_t)kk * 8 * 64 + lane) * 8;
#pragma unroll
        for (int nt = 0; nt < 8; ++nt) {
            s16x8 bn = *(const s16x8*)(bp + nt * 512);
            accN[nt] = __builtin_amdgcn_mfma_f32_16x16x32_bf16(a, bn, accN[nt], 0, 0, 0);
            s16x8 br = *(const s16x8*)(rp + nt * 512);
            accR[nt] = __builtin_amdgcn_mfma_f32_16x16x32_bf16(a, br, accR[nt], 0, 0, 0);
        }
    }

#pragma unroll
    for (int nt = 0; nt < 8; ++nt) {
        int col = nt * 16 + m;
        float bn = bneg[col], br = broot[col];
        int rbase = n0 + wv * 16 + quad * 4;
#pragma unroll
        for (int r = 0; r < 4; ++r) {
            int node = rbase + r;
            if (node < N_NODES) {
                Yb[(size_t)node * 128 + col] = __float2bfloat16(accN[nt][r] + bn);
                float v = accR[nt][r] + br;
                out[(size_t)node * 128 + col] = (v > 0.f) ? v : (__expf(v) - 1.f);
            }
        }
    }
}

// ---------------------------------------------------------------------------
// CSR build: memset -> histogram -> 3-pass scan -> payload scatter
// ---------------------------------------------------------------------------
__global__ __launch_bounds__(256) void histogram(const int* __restrict__ idx,
                                                 int* __restrict__ cnt) {
    int e = blockIdx.x * 256 + threadIdx.x;
    if (e < N_EDGES) atomicAdd(&cnt[idx[e]], 1);
}

__global__ __launch_bounds__(256) void scan_block_sums(const int* __restrict__ cnt,
                                                       int* __restrict__ bsum) {
    __shared__ int ws[4];
    int tid = threadIdx.x, lane = tid & 63, wid = tid >> 6;
    int i = blockIdx.x * 256 + tid;
    int v = (i < N_NODES) ? cnt[i] : 0;
#pragma unroll
    for (int d = 32; d > 0; d >>= 1) v += __shfl_down(v, d);
    if (lane == 0) ws[wid] = v;
    __syncthreads();
    if (tid == 0) bsum[blockIdx.x] = ws[0] + ws[1] + ws[2] + ws[3];
}

__global__ __launch_bounds__(512) void scan_bsums(int* __restrict__ bsum) {
    __shared__ int s[512];
    int tid = threadIdx.x;
    int v = (tid < NBLK) ? bsum[tid] : 0;
    s[tid] = v;
    __syncthreads();
    for (int d = 1; d < 512; d <<= 1) {
        int t = (tid >= d) ? s[tid - d] : 0;
        __syncthreads();
        s[tid] += t;
        __syncthreads();
    }
    if (tid < NBLK) bsum[tid] = s[tid] - v;   // exclusive
}

__global__ __launch_bounds__(256) void scan_final(const int* __restrict__ cnt,
                                                  const int* __restrict__ bsum,
                                                  int* __restrict__ off,
                                                  int* __restrict__ cursor) {
    __shared__ int wsum[4];
    int tid = threadIdx.x, lane = tid & 63, wid = tid >> 6;
    int i = blockIdx.x * 256 + tid;
    int v = (i < N_NODES) ? cnt[i] : 0;
    int x = v;
#pragma unroll
    for (int d = 1; d < 64; d <<= 1) {
        int t = __shfl_up(x, d);
        if (lane >= d) x += t;
    }
    if (lane == 63) wsum[wid] = x;
    __syncthreads();
    int wpre = 0;
#pragma unroll
    for (int j = 0; j < 4; ++j) wpre += (j < wid) ? wsum[j] : 0;
    int excl = bsum[blockIdx.x] + wpre + x - v;
    if (i < N_NODES) { off[i] = excl; cursor[i] = excl; }
}

// payload slot: {src:int, ea packed as 3x(f16,f16)} = 16B; dst in parallel array
__global__ __launch_bounds__(256) void scatter_edges(const int* __restrict__ idx,
                                                     const float* __restrict__ ea,
                                                     int* __restrict__ cursor,
                                                     uint4* __restrict__ pay,
                                                     int* __restrict__ dstA) {
    int e = blockIdx.x * 256 + threadIdx.x;
    if (e < N_EDGES) {
        int dst = idx[e];
        int src = idx[N_EDGES + e];
        const float* er = ea + (size_t)e * EDGE_DIM;
        unsigned p0 = f2h(er[0]) | (f2h(er[1]) << 16);
        unsigned p1 = f2h(er[2]) | (f2h(er[3]) << 16);
        unsigned p2 = f2h(er[4]) | (f2h(er[5]) << 16);
        int pos = atomicAdd(&cursor[dst], 1);
        uint4 pl = { (unsigned)src, p0, p1, p2 };
        pay[pos] = pl;
        dstA[pos] = dst;
    }
}

// ---------------------------------------------------------------------------
// Aggregate, edge-parallel v3:
//  - one wave per 64 consecutive CSR slots (uniform work, no degree tail)
//  - segment boundaries from dstA: one shfl+ballot -> 64-bit SGPR mask;
//    inner-loop boundary test is a SALU bit-test, flush node via v_readlane.
//    ZERO memory ops in the boundary path (v2's off[] walk forced vmcnt(0)
//    drains of the whole prefetch pipeline at every boundary).
//  - edge FMA work via v_dot2_f32_f16 (6 dot2 vs 12 fma per edge)
//  - Y-row gathers 24 deep (3 ping-pong batches of 8) in registers
// ---------------------------------------------------------------------------
__global__ __launch_bounds__(256) void aggregate(
    const uint4* __restrict__ pay,
    const int*  __restrict__ dstA,
    const float* __restrict__ Wneg,  // bottom 6 rows at 133*128
    const __hip_bfloat16* __restrict__ Yb,
    float* __restrict__ out)
{
    const int lane = threadIdx.x & 63;
    const int wid  = blockIdx.x * 4 + (threadIdx.x >> 6);
    const int e0   = wid * 64;

    // pack Wb (6 x 128 f32, this lane's channel pair) into f16 dot2 operands
    const float2* wb2 = (const float2*)(Wneg + 133 * 128);
    float2 w0 = wb2[0 * 64 + lane], w1 = wb2[1 * 64 + lane];
    float2 w2 = wb2[2 * 64 + lane], w3 = wb2[3 * 64 + lane];
    float2 w4 = wb2[4 * 64 + lane], w5 = wb2[5 * 64 + lane];
    h16x2 wx0 = {(_Float16)w0.x, (_Float16)w1.x};
    h16x2 wx1 = {(_Float16)w2.x, (_Float16)w3.x};
    h16x2 wx2 = {(_Float16)w4.x, (_Float16)w5.x};
    h16x2 wy0 = {(_Float16)w0.y, (_Float16)w1.y};
    h16x2 wy1 = {(_Float16)w2.y, (_Float16)w3.y};
    h16x2 wy2 = {(_Float16)w4.y, (_Float16)w5.y};

    const unsigned* Yu = (const unsigned*)Yb;   // 64 uints per Y row

    uint4 pl = pay[e0 + lane];                  // coalesced: whole chunk
    int src_l = (int)pl.x;
    int ea0 = (int)pl.y, ea1 = (int)pl.z, ea2 = (int)pl.w;
    int dst_l = dstA[e0 + lane];

    // boundary mask: bit c set iff edge e0+c is the last edge of its node
    // within this chunk (bit 63 always set -> final flush)
    int nd = __shfl_down(dst_l, 1);
    unsigned long long bm = __ballot((lane == 63) || (dst_l != nd));

    float accx = 0.f, accy = 0.f;

    auto edge_op = [&](unsigned yv, int c) {
        unsigned a0 = (unsigned)__builtin_amdgcn_readlane(ea0, c);
        unsigned a1 = (unsigned)__builtin_amdgcn_readlane(ea1, c);
        unsigned a2 = (unsigned)__builtin_amdgcn_readlane(ea2, c);
        float tx = bflo(yv), ty = bfhi(yv);
        tx = dot2f(a0, wx0, tx); ty = dot2f(a0, wy0, ty);
        tx = dot2f(a1, wx1, tx); ty = dot2f(a1, wy1, ty);
        tx = dot2f(a2, wx2, tx); ty = dot2f(a2, wy2, ty);
        tx = (tx > 0.f) ? tx : (__expf(tx) - 1.f);
        ty = (ty > 0.f) ? ty : (__expf(ty) - 1.f);
        accx += tx; accy += ty;
        if ((bm >> c) & 1ull) {                 // uniform SALU bit-test
            int n = __builtin_amdgcn_readlane(dst_l, c);
            float* orow = out + ((size_t)n << 7) + (lane << 1);
            atomicAdd(orow,     accx);
            atomicAdd(orow + 1, accy);
            accx = 0.f; accy = 0.f;
        }
    };

    auto load8 = [&](unsigned (&buf)[8], int pfbase) {
#pragma unroll
        for (int j = 0; j < 8; ++j) {
            int s = __builtin_amdgcn_readlane(src_l, pfbase + j);
            buf[j] = Yu[(size_t)s * 64 + lane];
        }
    };
    auto batch = [&](unsigned (&buf)[8], int cbase, int pfbase) {
#pragma unroll
        for (int j = 0; j < 8; ++j) {
            edge_op(buf[j], cbase + j);
            if (pfbase >= 0) {
                int s = __builtin_amdgcn_readlane(src_l, pfbase + j);
                buf[j] = Yu[(size_t)s * 64 + lane];
            }
        }
    };

    unsigned yA[8], yB[8], yC[8];
    load8(yA, 0); load8(yB, 8); load8(yC, 16);   // 24 loads in flight

    batch(yA,  0, 24);
    batch(yB,  8, 32);
    batch(yC, 16, 40);
    batch(yA, 24, 48);
    batch(yB, 32, 56);
    batch(yC, 40, -1);
    batch(yA, 48, -1);
    batch(yB, 56, -1);
}

extern "C" void kernel_launch(void* const* d_in, const int* in_sizes, int n_in,
                              void* d_out, int out_size, void* d_ws, size_t ws_size,
                              hipStream_t stream) {
    const float* x     = (const float*)d_in[0];
    const int*   idx   = (const int*)  d_in[1];
    const float* ea    = (const float*)d_in[2];
    const float* gs    = (const float*)d_in[3];
    const float* Wneg  = (const float*)d_in[4];
    const float* bneg  = (const float*)d_in[5];
    const float* Wroot = (const float*)d_in[6];
    const float* broot = (const float*)d_in[7];
    float* out = (float*)d_out;

    // ws layout (16B-aligned sections):
    //   Yb      : N*128 bf16           25.6 MB
    //   cnt/off/cur : N int each        1.2 MB
    //   bsum    : NBLK int (pad 2KB)
    //   pay     : E * 16B              25.6 MB
    //   dstA    : E * 4B                6.4 MB
    //   Pneg/Proot : 40 KB each
    char* w = (char*)d_ws;
    __hip_bfloat16* Yb = (__hip_bfloat16*)w;      w += (size_t)N_NODES * 128 * 2;
    int* cnt  = (int*)w;                          w += (size_t)N_NODES * 4;
    int* off  = (int*)w;                          w += (size_t)N_NODES * 4;
    int* cur  = (int*)w;                          w += (size_t)N_NODES * 4;
    int* bsum = (int*)w;                          w += 2048;
    uint4* pay = (uint4*)w;                       w += (size_t)N_EDGES * 16;
    int* dstA = (int*)w;                          w += (size_t)N_EDGES * 4;
    unsigned short* Pneg  = (unsigned short*)w;   w += (size_t)NKSTEP * 8 * 64 * 8 * 2;
    unsigned short* Proot = (unsigned short*)w;

    const int nb_edges = (N_EDGES + 255) / 256;

    repack_w<<<80, 64, 0, stream>>>(Wneg, Wroot, Pneg, Proot);
    node_gemm_mfma<<<(N_NODES + 63) / 64, 256, 0, stream>>>(
        x, gs, Pneg, Proot, bneg, broot, Yb, out);
    hipMemsetAsync(cnt, 0, (size_t)N_NODES * 4, stream);
    histogram<<<nb_edges, 256, 0, stream>>>(idx, cnt);
    scan_block_sums<<<NBLK, 256, 0, stream>>>(cnt, bsum);
    scan_bsums<<<1, 512, 0, stream>>>(bsum);
    scan_final<<<NBLK, 256, 0, stream>>>(cnt, bsum, off, cur);
    scatter_edges<<<nb_edges, 256, 0, stream>>>(idx, ea, cur, pay, dstA);
    aggregate<<<N_CHUNKS / 4, 256, 0, stream>>>(pay, dstA, Wneg, Yb, out);
}